// Round 18
// baseline (90.945 us; speedup 1.0000x reference)
//
#include <hip/hip_runtime.h>
#include <stdint.h>

typedef short short8 __attribute__((ext_vector_type(8)));
typedef float f32x4 __attribute__((ext_vector_type(4)));

__device__ inline float b2f(unsigned short u) {
    union { float f; uint32_t i; } v; v.i = ((uint32_t)u) << 16; return v.f;
}
__device__ inline unsigned short f2b(float f) {
    union { float f; uint32_t i; } v; v.f = f;
    uint32_t r = v.i + 0x7FFFu + ((v.i >> 16) & 1u);
    return (unsigned short)(r >> 16);
}

#define BB 8
#define NN 1024
#define HH 128
#define EE 4
#define MROWS (BB * NN)      // 8192
#define NBR_CAP 96
#define CMAX 80              // clamp real count; pad to multiple of 16 (<=96 exactly)

// XCD-affinity: all work touching graph b runs on blocks with blockIdx%8==b.

// 16 neighbors of one list: lanes 0-31 take even slots, 32-63 odd slots,
// each lane reads 8B (4 cols). 8 independent row-loads per 16-list.
__device__ __forceinline__ void gath16(
    const unsigned short* __restrict__ cl, int q,
    const uint2* __restrict__ rowbase,   // row stride = 32 uint2
    uint32_t sh, int lo,                 // (l>>5)*16, l&31
    float& a0, float& a1, float& a2, float& a3)
{
    uint4 ia = *(const uint4*)(cl + q);
    uint4 ib = *(const uint4*)(cl + q + 8);
    uint32_t j0 = (ia.x >> sh) & 0xffffu, j1 = (ia.y >> sh) & 0xffffu;
    uint32_t j2 = (ia.z >> sh) & 0xffffu, j3 = (ia.w >> sh) & 0xffffu;
    uint32_t j4 = (ib.x >> sh) & 0xffffu, j5 = (ib.y >> sh) & 0xffffu;
    uint32_t j6 = (ib.z >> sh) & 0xffffu, j7 = (ib.w >> sh) & 0xffffu;
    uint2 v0 = rowbase[(size_t)j0 * 32 + lo];
    uint2 v1 = rowbase[(size_t)j1 * 32 + lo];
    uint2 v2 = rowbase[(size_t)j2 * 32 + lo];
    uint2 v3 = rowbase[(size_t)j3 * 32 + lo];
    uint2 v4 = rowbase[(size_t)j4 * 32 + lo];
    uint2 v5 = rowbase[(size_t)j5 * 32 + lo];
    uint2 v6 = rowbase[(size_t)j6 * 32 + lo];
    uint2 v7 = rowbase[(size_t)j7 * 32 + lo];
    a0 += b2f((unsigned short)(v0.x & 0xffffu)); a1 += b2f((unsigned short)(v0.x >> 16));
    a2 += b2f((unsigned short)(v0.y & 0xffffu)); a3 += b2f((unsigned short)(v0.y >> 16));
    a0 += b2f((unsigned short)(v1.x & 0xffffu)); a1 += b2f((unsigned short)(v1.x >> 16));
    a2 += b2f((unsigned short)(v1.y & 0xffffu)); a3 += b2f((unsigned short)(v1.y >> 16));
    a0 += b2f((unsigned short)(v2.x & 0xffffu)); a1 += b2f((unsigned short)(v2.x >> 16));
    a2 += b2f((unsigned short)(v2.y & 0xffffu)); a3 += b2f((unsigned short)(v2.y >> 16));
    a0 += b2f((unsigned short)(v3.x & 0xffffu)); a1 += b2f((unsigned short)(v3.x >> 16));
    a2 += b2f((unsigned short)(v3.y & 0xffffu)); a3 += b2f((unsigned short)(v3.y >> 16));
    a0 += b2f((unsigned short)(v4.x & 0xffffu)); a1 += b2f((unsigned short)(v4.x >> 16));
    a2 += b2f((unsigned short)(v4.y & 0xffffu)); a3 += b2f((unsigned short)(v4.y >> 16));
    a0 += b2f((unsigned short)(v5.x & 0xffffu)); a1 += b2f((unsigned short)(v5.x >> 16));
    a2 += b2f((unsigned short)(v5.y & 0xffffu)); a3 += b2f((unsigned short)(v5.y >> 16));
    a0 += b2f((unsigned short)(v6.x & 0xffffu)); a1 += b2f((unsigned short)(v6.x >> 16));
    a2 += b2f((unsigned short)(v6.y & 0xffffu)); a3 += b2f((unsigned short)(v6.y >> 16));
    a0 += b2f((unsigned short)(v7.x & 0xffffu)); a1 += b2f((unsigned short)(v7.x >> 16));
    a2 += b2f((unsigned short)(v7.y & 0xffffu)); a3 += b2f((unsigned short)(v7.y >> 16));
}

// ============ combo: sparsify (blocks 0..8191) + setup (blocks 8192..12287) ============
__global__ __launch_bounds__(256) void combo(
    const float* __restrict__ adj, unsigned short* __restrict__ cols,
    int* __restrict__ cnt,
    const float* __restrict__ nf, const float* __restrict__ We,
    const float* __restrict__ Wih, const float* __restrict__ Whh,
    const float* __restrict__ bih, const float* __restrict__ bhh,
    const float* __restrict__ W1, const float* __restrict__ W2,
    float* __restrict__ h, unsigned short* __restrict__ hbA,
    unsigned short* __restrict__ hbB, unsigned short* __restrict__ nfb,
    unsigned short* __restrict__ wcf, unsigned short* __restrict__ wgf,
    unsigned short* __restrict__ w1f, unsigned short* __restrict__ w2f,
    float* __restrict__ bg)
{
    if (blockIdx.x < 8192) {
        int blk = blockIdx.x;
        int gb = blk & 7, q = blk >> 3;
        int row = gb * 4096 + q * 4 + (threadIdx.x >> 6);
        int l = threadIdx.x & 63;
        const float* ar = adj + (size_t)row * NN;
        unsigned short* cr = cols + (size_t)row * NBR_CAP;
        int c = 0;
        for (int it = 0; it < 4; ++it) {
            float4 v = *(const float4*)(ar + it * 256 + l * 4);
            const float* vp = &v.x;
            #pragma unroll
            for (int p = 0; p < 4; ++p) {
                float x = vp[p];
                unsigned long long m = __ballot(x != 0.f);
                if (x != 0.f) {
                    int idx = c + __popcll(m & ((1ull << l) - 1ull));
                    if (idx < CMAX) cr[idx] = (unsigned short)(it * 256 + l * 4 + p);
                }
                c += __popcll(m);
            }
        }
        // pad to multiple of 16 (min 16) with pointers to shared zero row:
        // local idx (8-b)<<10 -> global row 8192. cs<=80, cs+pad<=96=NBR_CAP.
        int bb = row >> 12;
        int cs = c < CMAX ? c : CMAX;
        int pad = (16 - (cs & 15)) & 15;
        if (cs == 0) pad = 16;
        if (l < pad) cr[cs + l] = (unsigned short)((8 - bb) << 10);
        if (l == 0) cnt[row] = cs + pad;
        return;
    }
    int blk2 = blockIdx.x - 8192;            // 0..4095
    int gb = blk2 & 7, q = blk2 >> 3;        // q in 0..511
    int tid = (gb * 512 + q) * 256 + threadIdx.x;   // bijection over 0..1,048,575
    {
        float v = nf[tid];
        h[tid] = v;
        unsigned short b = f2b(v);
        hbA[tid] = b;
        nfb[tid] = b;
    }
    if (tid < 128) {  // zero row 8192 in both hb buffers
        hbA[(size_t)MROWS * 128 + tid] = 0;
        hbB[(size_t)MROWS * 128 + tid] = 0;
    }
    // wgf: Wg(512 x 256) fragment-major (NF=32, s=0..7); gate cols: r|z|i_n|h_n
    if (tid < 131072) {
        int j = tid & 7, l = (tid >> 3) & 63, f = (tid >> 9) & 31, s = tid >> 14;
        int col = f * 16 + (l & 15);
        int k   = s * 32 + ((l >> 4) << 3) + j;
        int kr = k & 127;
        float v;
        if (col < 256)      v = (k < 128) ? Wih[col * 128 + kr] : Whh[col * 128 + kr];
        else if (col < 384) v = (k < 128) ? Wih[col * 128 + kr] : 0.f;
        else                v = (k < 128) ? 0.f : Whh[(col - 128) * 128 + kr];
        wgf[tid] = f2b(v);
    }
    // wcf: Wc(128 x 512) fragment-major (NF=8, s=0..15); Wc[c][(e,hh)] = We[e][c][hh]
    if (tid < 65536) {
        int j = tid & 7, l = (tid >> 3) & 63, f = (tid >> 9) & 7, s = tid >> 12;
        int col = f * 16 + (l & 15);
        int k   = s * 32 + ((l >> 4) << 3) + j;
        int e = k >> 7, hh2 = k & 127;
        wcf[tid] = f2b(We[(e << 14) + (col << 7) + hh2]);
    }
    // w1f: W1(128 x 256) (NF=8, s=0..7)
    if (tid < 32768) {
        int j = tid & 7, l = (tid >> 3) & 63, f = (tid >> 9) & 7, s = tid >> 12;
        int col = f * 16 + (l & 15);
        int k   = s * 32 + ((l >> 4) << 3) + j;
        w1f[tid] = f2b(W1[col * 256 + k]);
    }
    // w2f: W2(128 x 128) (NF=8, s=0..3)
    if (tid < 16384) {
        int j = tid & 7, l = (tid >> 3) & 63, f = (tid >> 9) & 7, s = tid >> 12;
        int col = f * 16 + (l & 15);
        int k   = s * 32 + ((l >> 4) << 3) + j;
        w2f[tid] = f2b(W2[col * 128 + k]);
    }
    // bg[512]: combined bias (r,z: bih+bhh; i_n: bih; h_n: bhh)
    if (tid < 512) {
        int sec = tid >> 7, k = tid & 127;
        float v;
        if (sec == 0)      v = bih[k] + bhh[k];
        else if (sec == 1) v = bih[128 + k] + bhh[128 + k];
        else if (sec == 2) v = bih[256 + k];
        else               v = bhh[256 + k];
        bg[tid] = v;
    }
}

// ============ fstep<LAST>: gather(LDS) + combine + gates + register GRU [+ MLP tail] ============
// 512 blocks x 512 thr (8 waves), 16 rows/block, ~29.7KB LDS -> 2 blocks/CU.
// XCD-affine: graph b = blk%8. hb ping-pong across dispatches.
template<bool LAST>
__global__ __launch_bounds__(512, 4) void fstep(
    const unsigned short* __restrict__ cols, const int* __restrict__ cnt,
    const unsigned short* __restrict__ hb_in, unsigned short* __restrict__ hb_out,
    float* __restrict__ h_g,
    const unsigned short* __restrict__ wcf, const unsigned short* __restrict__ wgf,
    const float* __restrict__ bg,
    const unsigned short* __restrict__ nfb,
    const unsigned short* __restrict__ w1f, const float* __restrict__ b1,
    const unsigned short* __restrict__ w2f, const float* __restrict__ b2,
    float* __restrict__ out)
{
    __shared__ unsigned short s_ab[16 * 520];  // 16,640 B (gather output, K=512)
    __shared__ unsigned short s_hb[16 * 136];  //  4,352 B (old h; new h when LAST)
    __shared__ unsigned short s_m[16 * 136];   //  4,352 B (m; y when LAST)
    __shared__ unsigned short s_nf[16 * 136];  //  4,352 B (LAST only)
    const int t = threadIdx.x, l = t & 63, wv = t >> 6;
    const int lr = l & 15;
    const int ak = (l >> 4) * 8;
    const int b = blockIdx.x & 7;
    const int i0 = (blockIdx.x >> 3) * 16;
    const int bm = (b << 10) + i0;
    const int kk = wv * 16 + lr;

    const float bgr = bg[kk], bgz = bg[128 + kk], bgn = bg[256 + kk], bgh = bg[384 + kk];

    // ---- stage s_hb (own rows, old h) + s_nf (LAST only) ----
    if (t < 256) {
        int row = t >> 4, ch = (t & 15) * 8;
        *(short8*)&s_hb[row * 136 + ch] = *(const short8*)(hb_in + (size_t)(bm + row) * 128 + ch);
    } else if (LAST) {
        int t2 = t - 256, row = t2 >> 4, ch = (t2 & 15) * 8;
        *(short8*)&s_nf[row * 136 + ch] = *(const short8*)(nfb + (size_t)(bm + row) * 128 + ch);
    }

    // ---- gather: wave wv owns 8 lists; half-wave split (8 x 8B loads per 16-list) ----
    const uint2* rowbase = (const uint2*)(hb_in + ((size_t)(b << 10)) * 128);
    const uint32_t sh = (l >> 5) << 4;   // 0 or 16
    const int lo = l & 31;
    #pragma unroll
    for (int pp = 0; pp < 8; pp += 2) {
        int pr0 = wv * 8 + pp,  rl0 = pr0 >> 2, e0 = pr0 & 3;
        int pr1 = pr0 + 1,      rl1 = pr1 >> 2, e1 = pr1 & 3;
        int ar0 = (((b << 2) + e0) << 10) + i0 + rl0;
        int ar1 = (((b << 2) + e1) << 10) + i0 + rl1;
        int c0 = cnt[ar0], c1 = cnt[ar1];          // multiples of 16, >=16
        const unsigned short* cl0 = cols + (size_t)ar0 * NBR_CAP;
        const unsigned short* cl1 = cols + (size_t)ar1 * NBR_CAP;
        float a00 = 0.f, a01 = 0.f, a02 = 0.f, a03 = 0.f;
        float a10 = 0.f, a11 = 0.f, a12 = 0.f, a13 = 0.f;
        // first 16 of BOTH lists — one basic block, 16 loads in flight
        gath16(cl0, 0, rowbase, sh, lo, a00, a01, a02, a03);
        gath16(cl1, 0, rowbase, sh, lo, a10, a11, a12, a13);
        // rare tails (wave-uniform branches)
        for (int q = 16; q < c0; q += 16) gath16(cl0, q, rowbase, sh, lo, a00, a01, a02, a03);
        for (int q = 16; q < c1; q += 16) gath16(cl1, q, rowbase, sh, lo, a10, a11, a12, a13);
        // combine even/odd halves (both halves cover the SAME 4 cols)
        a00 += __shfl_xor(a00, 32); a01 += __shfl_xor(a01, 32);
        a02 += __shfl_xor(a02, 32); a03 += __shfl_xor(a03, 32);
        a10 += __shfl_xor(a10, 32); a11 += __shfl_xor(a11, 32);
        a12 += __shfl_xor(a12, 32); a13 += __shfl_xor(a13, 32);
        if (l < 32) {
            uint32_t p0 = (uint32_t)f2b(a00) | ((uint32_t)f2b(a01) << 16);
            uint32_t p1 = (uint32_t)f2b(a02) | ((uint32_t)f2b(a03) << 16);
            uint32_t* d0 = (uint32_t*)&s_ab[rl0 * 520 + e0 * 128 + lo * 4];
            d0[0] = p0; d0[1] = p1;
            uint32_t q0 = (uint32_t)f2b(a10) | ((uint32_t)f2b(a11) << 16);
            uint32_t q1 = (uint32_t)f2b(a12) | ((uint32_t)f2b(a13) << 16);
            uint32_t* d1 = (uint32_t*)&s_ab[rl1 * 520 + e1 * 128 + lo * 4];
            d1[0] = q0; d1[1] = q1;
        }
    }
    __syncthreads();

    // ---- phase B: m(16x128) = s_ab(16x512) @ Wc^T ; wave wv -> col frag wv ----
    f32x4 accB = {};
    #pragma unroll
    for (int s = 0; s < 16; ++s) {
        short8 af = *(const short8*)&s_ab[lr * 520 + s * 32 + ak];
        short8 bc = *(const short8*)(wcf + (((size_t)s * 8 + wv) * 64 + l) * 8);
        accB = __builtin_amdgcn_mfma_f32_16x16x32_bf16(af, bc, accB, 0, 0, 0);
    }
    #pragma unroll
    for (int r = 0; r < 4; ++r)
        s_m[((l >> 4) * 4 + r) * 136 + kk] = f2b(accB[r]);
    __syncthreads();

    // ---- phase C: gates; wave wv uses B-frags f = g*8+wv -> all 4 gates in-lane ----
    f32x4 accC[4] = {};
    #pragma unroll
    for (int s = 0; s < 8; ++s) {
        short8 af = (s < 4)
            ? *(const short8*)&s_m[lr * 136 + s * 32 + ak]
            : *(const short8*)&s_hb[lr * 136 + (s - 4) * 32 + ak];
        #pragma unroll
        for (int g = 0; g < 4; ++g) {
            short8 cf = *(const short8*)(wgf + (((size_t)s * 32 + g * 8 + wv) * 64 + l) * 8);
            accC[g] = __builtin_amdgcn_mfma_f32_16x16x32_bf16(af, cf, accC[g], 0, 0, 0);
        }
    }

    // ---- phase D: register GRU ----
    float hv4[4];
    #pragma unroll
    for (int r = 0; r < 4; ++r) {
        size_t gidx = (size_t)(bm + (l >> 4) * 4 + r) * 128 + kk;
        float ho = h_g[gidx];
        float rr = 1.f / (1.f + __expf(-(accC[0][r] + bgr)));
        float zz = 1.f / (1.f + __expf(-(accC[1][r] + bgz)));
        float n  = tanhf(accC[2][r] + bgn + rr * (accC[3][r] + bgh));
        float hv = (1.f - zz) * n + zz * ho;
        hv4[r] = hv;
        if (!LAST) {
            h_g[gidx] = hv;
            hb_out[gidx] = f2b(hv);
        }
    }

    if constexpr (LAST) {
        // ---- MLP tail: y = relu([nf|h]@W1^T+b1); out = y@W2^T+b2 (own rows) ----
        __syncthreads();   // all phase-C reads of s_hb/s_m complete
        #pragma unroll
        for (int r = 0; r < 4; ++r)
            s_hb[((l >> 4) * 4 + r) * 136 + kk] = f2b(hv4[r]);
        __syncthreads();   // new h visible
        f32x4 accY = {};
        #pragma unroll
        for (int s = 0; s < 8; ++s) {
            short8 af = (s < 4)
                ? *(const short8*)&s_nf[lr * 136 + s * 32 + ak]
                : *(const short8*)&s_hb[lr * 136 + (s - 4) * 32 + ak];
            short8 bc = *(const short8*)(w1f + (((size_t)s * 8 + wv) * 64 + l) * 8);
            accY = __builtin_amdgcn_mfma_f32_16x16x32_bf16(af, bc, accY, 0, 0, 0);
        }
        float b1v = b1[kk];
        #pragma unroll
        for (int r = 0; r < 4; ++r) {
            float v = accY[r] + b1v;
            s_m[((l >> 4) * 4 + r) * 136 + kk] = f2b(v > 0.f ? v : 0.f);
        }
        __syncthreads();
        f32x4 accO = {};
        #pragma unroll
        for (int s = 0; s < 4; ++s) {
            short8 af = *(const short8*)&s_m[lr * 136 + s * 32 + ak];
            short8 bc = *(const short8*)(w2f + (((size_t)s * 8 + wv) * 64 + l) * 8);
            accO = __builtin_amdgcn_mfma_f32_16x16x32_bf16(af, bc, accO, 0, 0, 0);
        }
        float b2v = b2[kk];
        #pragma unroll
        for (int r = 0; r < 4; ++r)
            out[(size_t)(bm + (l >> 4) * 4 + r) * 128 + kk] = accO[r] + b2v;
    }
}

// ============ host launcher ============
extern "C" void kernel_launch(void* const* d_in, const int* in_sizes, int n_in,
                              void* d_out, int out_size, void* d_ws, size_t ws_size,
                              hipStream_t stream) {
    const float* nf  = (const float*)d_in[0];
    const float* adj = (const float*)d_in[1];
    const float* We  = (const float*)d_in[2];
    const float* Wih = (const float*)d_in[3];
    const float* Whh = (const float*)d_in[4];
    const float* bih = (const float*)d_in[5];
    const float* bhh = (const float*)d_in[6];
    const float* W1  = (const float*)d_in[7];
    const float* b1  = (const float*)d_in[8];
    const float* W2  = (const float*)d_in[9];
    const float* b2  = (const float*)d_in[10];
    float* out = (float*)d_out;

    char* p = (char*)d_ws;
    auto take = [&](size_t n) { char* r = p; p += (n + 255) & ~(size_t)255; return r; };
    int* cnt             = (int*)take(32768 * 4);
    unsigned short* cols = (unsigned short*)take((size_t)32768 * NBR_CAP * 2);
    float* h_g           = (float*)take((size_t)MROWS * 128 * 4);
    unsigned short* hbA  = (unsigned short*)take((size_t)(MROWS + 1) * 128 * 2);
    unsigned short* hbB  = (unsigned short*)take((size_t)(MROWS + 1) * 128 * 2);
    unsigned short* nfb  = (unsigned short*)take((size_t)MROWS * 128 * 2);
    unsigned short* wcf  = (unsigned short*)take(65536 * 2);
    unsigned short* wgf  = (unsigned short*)take(131072 * 2);
    unsigned short* w1f  = (unsigned short*)take(32768 * 2);
    unsigned short* w2f  = (unsigned short*)take(16384 * 2);
    float* bg            = (float*)take(512 * 4);

    combo<<<12288, 256, 0, stream>>>(adj, cols, cnt, nf, We, Wih, Whh, bih, bhh,
                                     W1, W2, h_g, hbA, hbB, nfb, wcf, wgf, w1f, w2f, bg);

    // hb ping-pong across dispatches (kernel boundary = grid barrier + flush)
    fstep<false><<<512, 512, 0, stream>>>(cols, cnt, hbA, hbB, h_g, wcf, wgf, bg,
                                          nfb, w1f, b1, w2f, b2, out);
    fstep<false><<<512, 512, 0, stream>>>(cols, cnt, hbB, hbA, h_g, wcf, wgf, bg,
                                          nfb, w1f, b1, w2f, b2, out);
    fstep<true><<<512, 512, 0, stream>>>(cols, cnt, hbA, hbB, h_g, wcf, wgf, bg,
                                         nfb, w1f, b1, w2f, b2, out);
}

// Round 19
// 83.631 us; speedup vs baseline: 1.0875x; 1.0875x over previous
//
#include <hip/hip_runtime.h>
#include <stdint.h>

typedef short short8 __attribute__((ext_vector_type(8)));
typedef float f32x4 __attribute__((ext_vector_type(4)));

__device__ inline float b2f(unsigned short u) {
    union { float f; uint32_t i; } v; v.i = ((uint32_t)u) << 16; return v.f;
}
__device__ inline unsigned short f2b(float f) {
    union { float f; uint32_t i; } v; v.f = f;
    uint32_t r = v.i + 0x7FFFu + ((v.i >> 16) & 1u);
    return (unsigned short)(r >> 16);
}

#define BB 8
#define NN 1024
#define HH 128
#define EE 4
#define MROWS (BB * NN)      // 8192
#define NBR_CAP 96
#define CMAX 80              // clamp real count; pad to multiple of 16 (<=96 exactly)

// XCD-affinity: all work touching graph b runs on blocks with blockIdx%8==b
// (HW round-robins workgroups across the 8 XCDs). Perf-only assumption (G16-safe).

// 16 gathered rows accumulated, all loads in one basic block (ILP)
__device__ __forceinline__ void burst16(
    const unsigned short* __restrict__ cl, int q,
    const unsigned short* __restrict__ hbase, float& a0, float& a1)
{
    uint4 ia = *(const uint4*)(cl + q);
    uint4 ib = *(const uint4*)(cl + q + 8);
    uint32_t v0 = *(const uint32_t*)(hbase + (size_t)(ia.x & 0xffffu) * HH);
    uint32_t v1 = *(const uint32_t*)(hbase + (size_t)(ia.x >> 16) * HH);
    uint32_t v2 = *(const uint32_t*)(hbase + (size_t)(ia.y & 0xffffu) * HH);
    uint32_t v3 = *(const uint32_t*)(hbase + (size_t)(ia.y >> 16) * HH);
    uint32_t v4 = *(const uint32_t*)(hbase + (size_t)(ia.z & 0xffffu) * HH);
    uint32_t v5 = *(const uint32_t*)(hbase + (size_t)(ia.z >> 16) * HH);
    uint32_t v6 = *(const uint32_t*)(hbase + (size_t)(ia.w & 0xffffu) * HH);
    uint32_t v7 = *(const uint32_t*)(hbase + (size_t)(ia.w >> 16) * HH);
    uint32_t v8 = *(const uint32_t*)(hbase + (size_t)(ib.x & 0xffffu) * HH);
    uint32_t v9 = *(const uint32_t*)(hbase + (size_t)(ib.x >> 16) * HH);
    uint32_t va = *(const uint32_t*)(hbase + (size_t)(ib.y & 0xffffu) * HH);
    uint32_t vb = *(const uint32_t*)(hbase + (size_t)(ib.y >> 16) * HH);
    uint32_t vc = *(const uint32_t*)(hbase + (size_t)(ib.z & 0xffffu) * HH);
    uint32_t vd = *(const uint32_t*)(hbase + (size_t)(ib.z >> 16) * HH);
    uint32_t ve = *(const uint32_t*)(hbase + (size_t)(ib.w & 0xffffu) * HH);
    uint32_t vf = *(const uint32_t*)(hbase + (size_t)(ib.w >> 16) * HH);
    a0 += b2f((unsigned short)(v0 & 0xffffu)); a1 += b2f((unsigned short)(v0 >> 16));
    a0 += b2f((unsigned short)(v1 & 0xffffu)); a1 += b2f((unsigned short)(v1 >> 16));
    a0 += b2f((unsigned short)(v2 & 0xffffu)); a1 += b2f((unsigned short)(v2 >> 16));
    a0 += b2f((unsigned short)(v3 & 0xffffu)); a1 += b2f((unsigned short)(v3 >> 16));
    a0 += b2f((unsigned short)(v4 & 0xffffu)); a1 += b2f((unsigned short)(v4 >> 16));
    a0 += b2f((unsigned short)(v5 & 0xffffu)); a1 += b2f((unsigned short)(v5 >> 16));
    a0 += b2f((unsigned short)(v6 & 0xffffu)); a1 += b2f((unsigned short)(v6 >> 16));
    a0 += b2f((unsigned short)(v7 & 0xffffu)); a1 += b2f((unsigned short)(v7 >> 16));
    a0 += b2f((unsigned short)(v8 & 0xffffu)); a1 += b2f((unsigned short)(v8 >> 16));
    a0 += b2f((unsigned short)(v9 & 0xffffu)); a1 += b2f((unsigned short)(v9 >> 16));
    a0 += b2f((unsigned short)(va & 0xffffu)); a1 += b2f((unsigned short)(va >> 16));
    a0 += b2f((unsigned short)(vb & 0xffffu)); a1 += b2f((unsigned short)(vb >> 16));
    a0 += b2f((unsigned short)(vc & 0xffffu)); a1 += b2f((unsigned short)(vc >> 16));
    a0 += b2f((unsigned short)(vd & 0xffffu)); a1 += b2f((unsigned short)(vd >> 16));
    a0 += b2f((unsigned short)(ve & 0xffffu)); a1 += b2f((unsigned short)(ve >> 16));
    a0 += b2f((unsigned short)(vf & 0xffffu)); a1 += b2f((unsigned short)(vf >> 16));
}

// ============ combo: sparsify (blocks 0..8191) + setup (blocks 8192..12287) ============
__global__ __launch_bounds__(256) void combo(
    const float* __restrict__ adj, unsigned short* __restrict__ cols,
    int* __restrict__ cnt,
    const float* __restrict__ nf, const float* __restrict__ We,
    const float* __restrict__ Wih, const float* __restrict__ Whh,
    const float* __restrict__ bih, const float* __restrict__ bhh,
    const float* __restrict__ W1, const float* __restrict__ W2,
    float* __restrict__ h, unsigned short* __restrict__ hbA,
    unsigned short* __restrict__ hbB, unsigned short* __restrict__ nfb,
    unsigned short* __restrict__ wcf, unsigned short* __restrict__ wgf,
    unsigned short* __restrict__ w1f, unsigned short* __restrict__ w2f,
    float* __restrict__ bg)
{
    if (blockIdx.x < 8192) {
        // swizzle: graph gb = blk%8 -> XCD gb; q = blk/8 picks 4-row group within graph
        int blk = blockIdx.x;
        int gb = blk & 7, q = blk >> 3;
        int row = gb * 4096 + q * 4 + (threadIdx.x >> 6);
        int l = threadIdx.x & 63;
        const float* ar = adj + (size_t)row * NN;
        unsigned short* cr = cols + (size_t)row * NBR_CAP;
        int c = 0;
        for (int it = 0; it < 4; ++it) {
            float4 v = *(const float4*)(ar + it * 256 + l * 4);
            const float* vp = &v.x;
            #pragma unroll
            for (int p = 0; p < 4; ++p) {
                float x = vp[p];
                unsigned long long m = __ballot(x != 0.f);
                if (x != 0.f) {
                    int idx = c + __popcll(m & ((1ull << l) - 1ull));
                    if (idx < CMAX) cr[idx] = (unsigned short)(it * 256 + l * 4 + p);
                }
                c += __popcll(m);
            }
        }
        // pad to multiple of 16 (min 16) with pointers to shared zero row:
        // local idx (8-b)<<10 -> global row 8192. cs<=80, cs+pad<=96=NBR_CAP.
        int bb = row >> 12;
        int cs = c < CMAX ? c : CMAX;
        int pad = (16 - (cs & 15)) & 15;
        if (cs == 0) pad = 16;
        if (l < pad) cr[cs + l] = (unsigned short)((8 - bb) << 10);
        if (l == 0) cnt[row] = cs + pad;
        return;
    }
    // setup swizzle: graph gb = blk2%8 -> XCD gb; 512 blocks per graph
    int blk2 = blockIdx.x - 8192;            // 0..4095
    int gb = blk2 & 7, q = blk2 >> 3;        // q in 0..511
    int tid = (gb * 512 + q) * 256 + threadIdx.x;   // bijection over 0..1,048,575
    {
        float v = nf[tid];
        h[tid] = v;
        unsigned short b = f2b(v);
        hbA[tid] = b;
        nfb[tid] = b;
    }
    if (tid < 128) {  // zero row 8192 in both hb buffers
        hbA[(size_t)MROWS * 128 + tid] = 0;
        hbB[(size_t)MROWS * 128 + tid] = 0;
    }
    // wgf: Wg(512 x 256) fragment-major (NF=32, s=0..7); gate cols: r|z|i_n|h_n
    if (tid < 131072) {
        int j = tid & 7, l = (tid >> 3) & 63, f = (tid >> 9) & 31, s = tid >> 14;
        int col = f * 16 + (l & 15);
        int k   = s * 32 + ((l >> 4) << 3) + j;
        int kr = k & 127;
        float v;
        if (col < 256)      v = (k < 128) ? Wih[col * 128 + kr] : Whh[col * 128 + kr];
        else if (col < 384) v = (k < 128) ? Wih[col * 128 + kr] : 0.f;
        else                v = (k < 128) ? 0.f : Whh[(col - 128) * 128 + kr];
        wgf[tid] = f2b(v);
    }
    // wcf: Wc(128 x 512) fragment-major (NF=8, s=0..15); Wc[c][(e,hh)] = We[e][c][hh]
    if (tid < 65536) {
        int j = tid & 7, l = (tid >> 3) & 63, f = (tid >> 9) & 7, s = tid >> 12;
        int col = f * 16 + (l & 15);
        int k   = s * 32 + ((l >> 4) << 3) + j;
        int e = k >> 7, hh2 = k & 127;
        wcf[tid] = f2b(We[(e << 14) + (col << 7) + hh2]);
    }
    // w1f: W1(128 x 256) (NF=8, s=0..7)
    if (tid < 32768) {
        int j = tid & 7, l = (tid >> 3) & 63, f = (tid >> 9) & 7, s = tid >> 12;
        int col = f * 16 + (l & 15);
        int k   = s * 32 + ((l >> 4) << 3) + j;
        w1f[tid] = f2b(W1[col * 256 + k]);
    }
    // w2f: W2(128 x 128) (NF=8, s=0..3)
    if (tid < 16384) {
        int j = tid & 7, l = (tid >> 3) & 63, f = (tid >> 9) & 7, s = tid >> 12;
        int col = f * 16 + (l & 15);
        int k   = s * 32 + ((l >> 4) << 3) + j;
        w2f[tid] = f2b(W2[col * 128 + k]);
    }
    // bg[512]: combined bias (r,z: bih+bhh; i_n: bih; h_n: bhh)
    if (tid < 512) {
        int sec = tid >> 7, k = tid & 127;
        float v;
        if (sec == 0)      v = bih[k] + bhh[k];
        else if (sec == 1) v = bih[128 + k] + bhh[128 + k];
        else if (sec == 2) v = bih[256 + k];
        else               v = bhh[256 + k];
        bg[tid] = v;
    }
}

// ============ fstep<LAST>: gather(LDS) + combine + gates + register GRU [+ MLP tail] ============
// 512 blocks x 512 thr (8 waves), 16 rows/block, ~29.7KB LDS, VGPR<=128 -> 2 blocks/CU.
// XCD-affine: graph b = blk%8 (gather hits graph b's hb rows in XCD b's L2).
// hb ping-pong across dispatches (gather reads hb_in all-rows; GRU writes hb_out own-rows).
template<bool LAST>
__global__ __launch_bounds__(512, 4) void fstep(
    const unsigned short* __restrict__ cols, const int* __restrict__ cnt,
    const unsigned short* __restrict__ hb_in, unsigned short* __restrict__ hb_out,
    float* __restrict__ h_g,
    const unsigned short* __restrict__ wcf, const unsigned short* __restrict__ wgf,
    const float* __restrict__ bg,
    const unsigned short* __restrict__ nfb,
    const unsigned short* __restrict__ w1f, const float* __restrict__ b1,
    const unsigned short* __restrict__ w2f, const float* __restrict__ b2,
    float* __restrict__ out)
{
    __shared__ unsigned short s_ab[16 * 520];  // 16,640 B (gather output, K=512)
    __shared__ unsigned short s_hb[16 * 136];  //  4,352 B (old h; new h when LAST)
    __shared__ unsigned short s_m[16 * 136];   //  4,352 B (m; y when LAST)
    __shared__ unsigned short s_nf[16 * 136];  //  4,352 B (LAST only)
    const int t = threadIdx.x, l = t & 63, wv = t >> 6;
    const int lr = l & 15;
    const int ak = (l >> 4) * 8;
    // swizzle: graph b = blk%8 -> XCD b; rowblk = blk/8 in 0..63
    const int b = blockIdx.x & 7;
    const int i0 = (blockIdx.x >> 3) * 16;
    const int bm = (b << 10) + i0;
    const int kk = wv * 16 + lr;
    const int l2 = l * 2;

    const float bgr = bg[kk], bgz = bg[128 + kk], bgn = bg[256 + kk], bgh = bg[384 + kk];

    // ---- stage s_hb (own rows, old h) + s_nf (LAST only) ----
    if (t < 256) {
        int row = t >> 4, ch = (t & 15) * 8;
        *(short8*)&s_hb[row * 136 + ch] = *(const short8*)(hb_in + (size_t)(bm + row) * 128 + ch);
    } else if (LAST) {
        int t2 = t - 256, row = t2 >> 4, ch = (t2 & 15) * 8;
        *(short8*)&s_nf[row * 136 + ch] = *(const short8*)(nfb + (size_t)(bm + row) * 128 + ch);
    }

    // ---- gather: wave wv owns 8 lists; pairs with interleaved 16-bursts (32 loads in flight) ----
    const unsigned short* hbase = hb_in + ((size_t)(b << 10)) * 128 + l2;
    #pragma unroll
    for (int pp = 0; pp < 8; pp += 2) {
        int pr0 = wv * 8 + pp,  rl0 = pr0 >> 2, e0 = pr0 & 3;
        int pr1 = pr0 + 1,      rl1 = pr1 >> 2, e1 = pr1 & 3;
        int ar0 = (((b << 2) + e0) << 10) + i0 + rl0;
        int ar1 = (((b << 2) + e1) << 10) + i0 + rl1;
        int c0 = cnt[ar0], c1 = cnt[ar1];          // multiples of 16, >=16
        const unsigned short* cl0 = cols + (size_t)ar0 * NBR_CAP;
        const unsigned short* cl1 = cols + (size_t)ar1 * NBR_CAP;
        float a00 = 0.f, a01 = 0.f, a10 = 0.f, a11 = 0.f;
        // first 16 of BOTH lists — unconditional, one basic block
        burst16(cl0, 0, hbase, a00, a01);
        burst16(cl1, 0, hbase, a10, a11);
        // rare tails (c>16 for ~3% of lists; wave-uniform branches)
        for (int q = 16; q < c0; q += 16) burst16(cl0, q, hbase, a00, a01);
        for (int q = 16; q < c1; q += 16) burst16(cl1, q, hbase, a10, a11);
        *(uint32_t*)&s_ab[rl0 * 520 + e0 * 128 + l2] =
            (uint32_t)f2b(a00) | ((uint32_t)f2b(a01) << 16);
        *(uint32_t*)&s_ab[rl1 * 520 + e1 * 128 + l2] =
            (uint32_t)f2b(a10) | ((uint32_t)f2b(a11) << 16);
    }
    __syncthreads();

    // ---- phase B: m(16x128) = s_ab(16x512) @ Wc^T ; wave wv -> col frag wv ----
    f32x4 accB = {};
    #pragma unroll
    for (int s = 0; s < 16; ++s) {
        short8 af = *(const short8*)&s_ab[lr * 520 + s * 32 + ak];
        short8 bc = *(const short8*)(wcf + (((size_t)s * 8 + wv) * 64 + l) * 8);
        accB = __builtin_amdgcn_mfma_f32_16x16x32_bf16(af, bc, accB, 0, 0, 0);
    }
    #pragma unroll
    for (int r = 0; r < 4; ++r)
        s_m[((l >> 4) * 4 + r) * 136 + kk] = f2b(accB[r]);
    __syncthreads();

    // ---- phase C: gates; wave wv uses B-frags f = g*8+wv -> all 4 gates in-lane ----
    f32x4 accC[4] = {};
    #pragma unroll
    for (int s = 0; s < 8; ++s) {
        short8 af = (s < 4)
            ? *(const short8*)&s_m[lr * 136 + s * 32 + ak]
            : *(const short8*)&s_hb[lr * 136 + (s - 4) * 32 + ak];
        #pragma unroll
        for (int g = 0; g < 4; ++g) {
            short8 cf = *(const short8*)(wgf + (((size_t)s * 32 + g * 8 + wv) * 64 + l) * 8);
            accC[g] = __builtin_amdgcn_mfma_f32_16x16x32_bf16(af, cf, accC[g], 0, 0, 0);
        }
    }

    // ---- phase D: register GRU ----
    float hv4[4];
    #pragma unroll
    for (int r = 0; r < 4; ++r) {
        size_t gidx = (size_t)(bm + (l >> 4) * 4 + r) * 128 + kk;
        float ho = h_g[gidx];
        float rr = 1.f / (1.f + __expf(-(accC[0][r] + bgr)));
        float zz = 1.f / (1.f + __expf(-(accC[1][r] + bgz)));
        float n  = tanhf(accC[2][r] + bgn + rr * (accC[3][r] + bgh));
        float hv = (1.f - zz) * n + zz * ho;
        hv4[r] = hv;
        if (!LAST) {
            h_g[gidx] = hv;
            hb_out[gidx] = f2b(hv);
        }
    }

    if constexpr (LAST) {
        // ---- MLP tail: y = relu([nf|h]@W1^T+b1); out = y@W2^T+b2 (own rows) ----
        __syncthreads();   // all phase-C reads of s_hb/s_m complete
        #pragma unroll
        for (int r = 0; r < 4; ++r)
            s_hb[((l >> 4) * 4 + r) * 136 + kk] = f2b(hv4[r]);
        __syncthreads();   // new h visible
        f32x4 accY = {};
        #pragma unroll
        for (int s = 0; s < 8; ++s) {
            short8 af = (s < 4)
                ? *(const short8*)&s_nf[lr * 136 + s * 32 + ak]
                : *(const short8*)&s_hb[lr * 136 + (s - 4) * 32 + ak];
            short8 bc = *(const short8*)(w1f + (((size_t)s * 8 + wv) * 64 + l) * 8);
            accY = __builtin_amdgcn_mfma_f32_16x16x32_bf16(af, bc, accY, 0, 0, 0);
        }
        float b1v = b1[kk];
        #pragma unroll
        for (int r = 0; r < 4; ++r) {
            float v = accY[r] + b1v;
            s_m[((l >> 4) * 4 + r) * 136 + kk] = f2b(v > 0.f ? v : 0.f);
        }
        __syncthreads();
        f32x4 accO = {};
        #pragma unroll
        for (int s = 0; s < 4; ++s) {
            short8 af = *(const short8*)&s_m[lr * 136 + s * 32 + ak];
            short8 bc = *(const short8*)(w2f + (((size_t)s * 8 + wv) * 64 + l) * 8);
            accO = __builtin_amdgcn_mfma_f32_16x16x32_bf16(af, bc, accO, 0, 0, 0);
        }
        float b2v = b2[kk];
        #pragma unroll
        for (int r = 0; r < 4; ++r)
            out[(size_t)(bm + (l >> 4) * 4 + r) * 128 + kk] = accO[r] + b2v;
    }
}

// ============ host launcher ============
extern "C" void kernel_launch(void* const* d_in, const int* in_sizes, int n_in,
                              void* d_out, int out_size, void* d_ws, size_t ws_size,
                              hipStream_t stream) {
    const float* nf  = (const float*)d_in[0];
    const float* adj = (const float*)d_in[1];
    const float* We  = (const float*)d_in[2];
    const float* Wih = (const float*)d_in[3];
    const float* Whh = (const float*)d_in[4];
    const float* bih = (const float*)d_in[5];
    const float* bhh = (const float*)d_in[6];
    const float* W1  = (const float*)d_in[7];
    const float* b1  = (const float*)d_in[8];
    const float* W2  = (const float*)d_in[9];
    const float* b2  = (const float*)d_in[10];
    float* out = (float*)d_out;

    char* p = (char*)d_ws;
    auto take = [&](size_t n) { char* r = p; p += (n + 255) & ~(size_t)255; return r; };
    int* cnt             = (int*)take(32768 * 4);
    unsigned short* cols = (unsigned short*)take((size_t)32768 * NBR_CAP * 2);
    float* h_g           = (float*)take((size_t)MROWS * 128 * 4);
    unsigned short* hbA  = (unsigned short*)take((size_t)(MROWS + 1) * 128 * 2);
    unsigned short* hbB  = (unsigned short*)take((size_t)(MROWS + 1) * 128 * 2);
    unsigned short* nfb  = (unsigned short*)take((size_t)MROWS * 128 * 2);
    unsigned short* wcf  = (unsigned short*)take(65536 * 2);
    unsigned short* wgf  = (unsigned short*)take(131072 * 2);
    unsigned short* w1f  = (unsigned short*)take(32768 * 2);
    unsigned short* w2f  = (unsigned short*)take(16384 * 2);
    float* bg            = (float*)take(512 * 4);

    combo<<<12288, 256, 0, stream>>>(adj, cols, cnt, nf, We, Wih, Whh, bih, bhh,
                                     W1, W2, h_g, hbA, hbB, nfb, wcf, wgf, w1f, w2f, bg);

    // hb ping-pong across dispatches (kernel boundary = grid barrier + flush)
    fstep<false><<<512, 512, 0, stream>>>(cols, cnt, hbA, hbB, h_g, wcf, wgf, bg,
                                          nfb, w1f, b1, w2f, b2, out);
    fstep<false><<<512, 512, 0, stream>>>(cols, cnt, hbB, hbA, h_g, wcf, wgf, bg,
                                          nfb, w1f, b1, w2f, b2, out);
    fstep<true><<<512, 512, 0, stream>>>(cols, cnt, hbA, hbB, h_g, wcf, wgf, bg,
                                         nfb, w1f, b1, w2f, b2, out);
}